// Round 19
// baseline (177.698 us; speedup 1.0000x reference)
//
#include <hip/hip_runtime.h>
#include <hip/hip_fp16.h>
#include <math.h>

#define B_  8
#define T_  4096
#define H_  512
#define FREQ 513
#define NW  576            // padded f (9 tiles of 64)
#define KE  576            // spec K: interleaved [re,im], padded; 9 tiles of 64
#define NFFT 1024
#define HOP 256
#define PAD 384
#define OUTB 1048576
#define CLAMP_MAXV 100.0f
#define SE_E ((size_t)T_ * KE)     // spec elems per batch (fp16)
#define EO_E ((size_t)T_ * NFFT)   // EO elems per batch

typedef __attribute__((ext_vector_type(8))) _Float16 f16x8;
typedef __attribute__((ext_vector_type(4))) float f32x4;

__device__ inline ushort f2h(float v) {
    _Float16 h = (_Float16)v;
    ushort u; __builtin_memcpy(&u, &h, 2); return u;
}
__device__ inline float h2f(ushort u) {
    _Float16 h; __builtin_memcpy(&h, &u, 2); return (float)h;
}

#define GLOAD_LDS16(g, l) __builtin_amdgcn_global_load_lds( \
    (const __attribute__((address_space(1))) unsigned int*)(g), \
    (__attribute__((address_space(3))) unsigned int*)(l), 16, 0, 0)

// ---------------- basis (fp16): Ab[r][c]; r<512: E half (k=2kk), r>=512: O half (k=2kk+1) --------
__global__ void basis_kernel(ushort* __restrict__ Ab) {
    int idx = blockIdx.x * 256 + threadIdx.x;   // [0, 1024*576)
    int r = idx / KE, c = idx - r * KE;
    int np = (r < 512) ? r : (r - 512);
    int kk = c >> 1;
    int k = (r < 512) ? (2 * kk) : (2 * kk + 1);
    float v = 0.f;
    bool valid = (r < 512) ? (kk <= 256) : (kk <= 255);
    if (valid) {
        int m = (np * k) & (NFFT - 1);
        float a = (float)m * 6.135923151542565e-3f;       // 2*pi/1024
        float sc = ((k == 0) || (k == 512)) ? (1.0f / NFFT) : (2.0f / NFFT);
        v = ((c & 1) ? -sinf(a) : cosf(a)) * sc;
    }
    Ab[idx] = f2h(v);
}

// ---------------- W prep (fp16): Wm/Wp [f(576)][k(512)] ----------------
__global__ void prepw_kernel(const float* __restrict__ W,
                             ushort* __restrict__ Wm, ushort* __restrict__ Wp) {
    int idx = blockIdx.x * 256 + threadIdx.x;
    if (idx >= NW * H_) return;
    int k = idx / NW, f = idx - k * NW;
    float vm = 0.f, vp = 0.f;
    if (f < FREQ) {
        vm = W[(size_t)k * (2 * FREQ) + f];
        vp = W[(size_t)k * (2 * FREQ) + FREQ + f];
    }
    size_t dst = (size_t)f * H_ + k;
    Wm[dst] = f2h(vm);
    Wp[dst] = f2h(vp);
}

// ---------------- x conversion (fp16, per bcount-chunk) ----------------
__global__ void convx_kernel(const float* __restrict__ x, ushort* __restrict__ xh, int b0) {
    size_t i8 = ((size_t)blockIdx.x * 256 + threadIdx.x) * 8;
    const float* xp = x + (size_t)b0 * T_ * H_ + i8;
    float4 v0 = *reinterpret_cast<const float4*>(xp);
    float4 v1 = *reinterpret_cast<const float4*>(xp + 4);
    float xv[8];
    *reinterpret_cast<float4*>(&xv[0]) = v0;
    *reinterpret_cast<float4*>(&xv[4]) = v1;
    ushort h[8];
    #pragma unroll
    for (int e = 0; e < 8; ++e) h[e] = f2h(xv[e]);
    *reinterpret_cast<ushort4*>(xh + i8)     = make_ushort4(h[0], h[1], h[2], h[3]);
    *reinterpret_cast<ushort4*>(xh + i8 + 4) = make_ushort4(h[4], h[5], h[6], h[7]);
}

// ---------------- nyquist-ish column f=512: fp32 GEMV -> SE tile 8 ----------------
__global__ void nyq_kernel(const ushort* __restrict__ xh,
                           const ushort* __restrict__ Wm, const ushort* __restrict__ Wp,
                           const float* __restrict__ bias,
                           ushort* __restrict__ SEh) {
    __shared__ ushort sW[1024];
    const int tid = threadIdx.x;
    const int b_local = blockIdx.y;
    const int t0 = blockIdx.x * 64;

    if (tid < 128) {
        const ushort* src = ((tid < 64) ? &Wm[(size_t)512 * H_] : &Wp[(size_t)512 * H_]);
        int base = (tid < 64) ? 0 : 512;
        int i = (tid & 63) * 8;
        *reinterpret_cast<ushort4*>(&sW[base + i])     = *reinterpret_cast<const ushort4*>(&src[i]);
        *reinterpret_cast<ushort4*>(&sW[base + i + 4]) = *reinterpret_cast<const ushort4*>(&src[i + 4]);
    }
    __syncthreads();

    const int tl = tid >> 2;
    const int q = tid & 3;
    const ushort* xr = xh + ((size_t)b_local * T_ + t0 + tl) * H_ + q * 128;
    float accm = 0.f, accp = 0.f;
    #pragma unroll
    for (int i = 0; i < 128; i += 8) {
        ushort4 xa = *reinterpret_cast<const ushort4*>(&xr[i]);
        ushort4 xb = *reinterpret_cast<const ushort4*>(&xr[i + 4]);
        ushort4 ma = *reinterpret_cast<const ushort4*>(&sW[q * 128 + i]);
        ushort4 mb = *reinterpret_cast<const ushort4*>(&sW[q * 128 + i + 4]);
        ushort4 pa = *reinterpret_cast<const ushort4*>(&sW[512 + q * 128 + i]);
        ushort4 pb = *reinterpret_cast<const ushort4*>(&sW[512 + q * 128 + i + 4]);
        ushort xs[8] = {xa.x, xa.y, xa.z, xa.w, xb.x, xb.y, xb.z, xb.w};
        ushort ms[8] = {ma.x, ma.y, ma.z, ma.w, mb.x, mb.y, mb.z, mb.w};
        ushort ps[8] = {pa.x, pa.y, pa.z, pa.w, pb.x, pb.y, pb.z, pb.w};
        #pragma unroll
        for (int e = 0; e < 8; ++e) {
            float xv = h2f(xs[e]);
            accm = fmaf(xv, h2f(ms[e]), accm);
            accp = fmaf(xv, h2f(ps[e]), accp);
        }
    }
    accm += __shfl_down(accm, 2); accm += __shfl_down(accm, 1);
    accp += __shfl_down(accp, 2); accp += __shfl_down(accp, 1);

    ushort vals[16] = {0};
    if (q == 0) {
        float mag = fminf(__expf(accm + bias[512]), CLAMP_MAXV);
        float phv = accp + bias[FREQ + 512];
        float sp, cp; __sincosf(phv, &sp, &cp);
        vals[0] = f2h(mag * cp);
        vals[1] = f2h(mag * sp);
    }
    ushort* drow = SEh + (size_t)b_local * SE_E + (size_t)8 * T_ * 64
                 + (size_t)(t0 + tl) * 64 + q * 16;
    *reinterpret_cast<ushort4*>(drow)      = make_ushort4(vals[0], vals[1], vals[2], vals[3]);
    *reinterpret_cast<ushort4*>(drow + 4)  = make_ushort4(vals[4], vals[5], vals[6], vals[7]);
    *reinterpret_cast<ushort4*>(drow + 8)  = make_ushort4(vals[8], vals[9], vals[10], vals[11]);
    *reinterpret_cast<ushort4*>(drow + 12) = make_ushort4(vals[12], vals[13], vals[14], vals[15]);
}

// ---------------- GEMM A (fp16 MFMA, 2-phase dbuf + counted vmcnt): 128t x 64f, BK=32 ----------
// grid: 1D bcount*256, XCD-swizzled (f fastest). Loads stay in flight across barriers (T4).
__global__ __launch_bounds__(256) void gemm_a_mfma(
    const ushort* __restrict__ xh,
    const ushort* __restrict__ Wm, const ushort* __restrict__ Wp,
    const float* __restrict__ bias,
    ushort* __restrict__ SEh, ushort* __restrict__ SOh)
{
    // ushort idx: X buf b @ b*4096 [128x32]; Wm buf b @ 8192+b*2048; Wp @ 12288+b*2048
    __shared__ __attribute__((aligned(16))) ushort SH[16384];

    const int tid = threadIdx.x;
    const int lane = tid & 63;
    const int w = tid >> 6;
    const int wr = w >> 1, wc = w & 1;
    const int g = lane >> 4;

    const int nwg = gridDim.x;
    const int wg = blockIdx.x;
    const int gwi = (wg & 7) * (nwg >> 3) + (wg >> 3);
    const int m0 = (gwi >> 3) * 128;
    const int f0 = (gwi & 7) * 64;

    const int rl = tid >> 2;                                  // 0..63 (staging row)
    const int swz = ((tid & 3) ^ ((tid >> 3) & 3)) * 8;       // pre-swizzled src chunk
    const int arow = lane & 15;

    f32x4 accM[4][2] = {};
    f32x4 accP[4][2] = {};
    char* pSH = (char*)SH;

    #define STAGE_A(b, k0) do { \
        GLOAD_LDS16(xh + (size_t)(m0 + rl) * H_ + (k0) + swz,       pSH + (b) * 8192 + w * 1024); \
        GLOAD_LDS16(xh + (size_t)(m0 + 64 + rl) * H_ + (k0) + swz,  pSH + (b) * 8192 + 4096 + w * 1024); \
        GLOAD_LDS16(Wm + (size_t)(f0 + rl) * H_ + (k0) + swz,       pSH + 16384 + (b) * 4096 + w * 1024); \
        GLOAD_LDS16(Wp + (size_t)(f0 + rl) * H_ + (k0) + swz,       pSH + 24576 + (b) * 4096 + w * 1024); \
    } while (0)

    STAGE_A(0, 0);
    #pragma unroll 2
    for (int step = 0; step < 16; ++step) {
        const int cur = step & 1;
        if (step < 15) {
            STAGE_A(cur ^ 1, (step + 1) * 32);
            asm volatile("s_waitcnt vmcnt(4)" ::: "memory");   // cur buffer complete; next in flight
        } else {
            asm volatile("s_waitcnt vmcnt(0)" ::: "memory");
        }
        __builtin_amdgcn_s_barrier();
        f16x8 ax[4], wm[2], wp[2];
        #pragma unroll
        for (int i = 0; i < 4; ++i) {
            int row = wr * 64 + i * 16 + arow;
            int cc = g ^ ((row >> 1) & 3);
            ax[i] = *reinterpret_cast<const f16x8*>(&SH[cur * 4096 + row * 32 + cc * 8]);
        }
        #pragma unroll
        for (int j = 0; j < 2; ++j) {
            int row = wc * 32 + j * 16 + arow;
            int cc = g ^ ((row >> 1) & 3);
            wm[j] = *reinterpret_cast<const f16x8*>(&SH[8192 + cur * 2048 + row * 32 + cc * 8]);
            wp[j] = *reinterpret_cast<const f16x8*>(&SH[12288 + cur * 2048 + row * 32 + cc * 8]);
        }
        #pragma unroll
        for (int i = 0; i < 4; ++i)
            #pragma unroll
            for (int j = 0; j < 2; ++j) {
                accM[i][j] = __builtin_amdgcn_mfma_f32_16x16x32_f16(ax[i], wm[j], accM[i][j], 0, 0, 0);
                accP[i][j] = __builtin_amdgcn_mfma_f32_16x16x32_f16(ax[i], wp[j], accP[i][j], 0, 0, 0);
            }
        __builtin_amdgcn_s_barrier();   // all reads of buf[cur] done before next stage overwrites it
    }
    #undef STAGE_A

    // ---- epilogue: nonlinearity (all f live), then 2-pass (SE, SO) LDS transpose ----
    const int ccol = lane & 15;
    const int rbase = (lane >> 4) * 4;
    const int b_local = m0 >> 12;
    const int t00blk = m0 & (T_ - 1);
    const size_t specoff = (size_t)b_local * SE_E;
    const size_t tilebase = (size_t)(f0 >> 6) * T_ * 64;

    #pragma unroll
    for (int j = 0; j < 2; ++j) {
        int f = f0 + wc * 32 + j * 16 + ccol;      // <= 511, always live
        float bm = bias[f];
        float bp = bias[FREQ + f];
        #pragma unroll
        for (int i = 0; i < 4; ++i)
            #pragma unroll
            for (int r = 0; r < 4; ++r) {
                float mag = fminf(__expf(accM[i][j][r] + bm), CLAMP_MAXV);
                float phv = accP[i][j][r] + bp;
                float sp, cp; __sincosf(phv, &sp, &cp);
                accM[i][j][r] = mag * cp;
                accP[i][j][r] = mag * sp;
            }
    }

    const int par_mine = ccol & 1;
    const int row0 = tid >> 3;           // 0..31
    const int c8 = (tid & 7) * 8;
    #pragma unroll
    for (int pass = 0; pass < 2; ++pass) {
        if (par_mine == pass) {
            #pragma unroll
            for (int j = 0; j < 2; ++j) {
                int u = wc * 32 + j * 16 + ccol;
                int kl = u & ~1;
                #pragma unroll
                for (int i = 0; i < 4; ++i) {
                    #pragma unroll
                    for (int r = 0; r < 4; ++r) {
                        int tl = wr * 64 + i * 16 + rbase + r;
                        *reinterpret_cast<ushort2*>(&SH[tl * 72 + kl]) =
                            make_ushort2(f2h(accM[i][j][r]), f2h(accP[i][j][r]));
                    }
                }
            }
        }
        __syncthreads();
        ushort* d = (pass ? SOh : SEh) + specoff + tilebase;
        #pragma unroll
        for (int q2 = 0; q2 < 4; ++q2) {
            int row = q2 * 32 + row0;
            ushort4 v0 = *reinterpret_cast<const ushort4*>(&SH[row * 72 + c8]);
            ushort4 v1 = *reinterpret_cast<const ushort4*>(&SH[row * 72 + c8 + 4]);
            ushort* dp = &d[(size_t)(t00blk + row) * 64 + c8];
            *reinterpret_cast<ushort4*>(dp) = v0;
            *reinterpret_cast<ushort4*>(dp + 4) = v1;
        }
        if (pass == 0) __syncthreads();
    }
}

// ---------------- stage 1 GEMM (fp16 MFMA, 2-phase dbuf + counted vmcnt): EO = basis.spec ------
// grid: (256, bcount), XCD-swizzled. Tile 128n x 128t, BK=32; E 18 / O 16 steps.
__global__ __launch_bounds__(256) void gemm_eo_mfma(
    const ushort* __restrict__ Ab,
    const ushort* __restrict__ SEh, const ushort* __restrict__ SOh,
    __half* __restrict__ EO)
{
    // ushort idx: A buf b @ b*4096 [128x32]; B buf b @ 8192 + b*4096 [128x32]
    __shared__ __attribute__((aligned(16))) ushort SH[16384];
    const int tid = threadIdx.x;
    const int lane = tid & 63;
    const int w = tid >> 6;
    const int wr = w >> 1, wc = w & 1;
    const int g = lane >> 4;

    const int wg = blockIdx.x;                 // 256 = 32t x 8n, % 8 == 0
    const int gwi = (wg & 7) * 32 + (wg >> 3);
    const int t0 = (gwi >> 3) * 128;           // contiguous t per XCD
    const int n0 = (gwi & 7) * 128;            // n fastest
    const int b_local = blockIdx.y;

    const ushort* Bsh = ((n0 < 512) ? SEh : SOh) + (size_t)b_local * SE_E;
    const int nsteps = (n0 < 512) ? (KE / 32) : (512 / 32);   // 18 or 16

    const int rl = tid >> 2;
    const int swz = ((tid & 3) ^ ((tid >> 3) & 3)) * 8;
    const int arow = lane & 15;

    f32x4 acc[4][4] = {};
    char* pSH = (char*)SH;

    #define STAGE_E(b, k0) do { \
        GLOAD_LDS16(Ab + (size_t)(n0 + rl) * KE + (k0) + swz,       pSH + (b) * 8192 + w * 1024); \
        GLOAD_LDS16(Ab + (size_t)(n0 + 64 + rl) * KE + (k0) + swz,  pSH + (b) * 8192 + 4096 + w * 1024); \
        GLOAD_LDS16(Bsh + ((size_t)((k0) >> 6) * T_ + t0 + rl) * 64 + ((k0) & 32) + swz,      pSH + 16384 + (b) * 8192 + w * 1024); \
        GLOAD_LDS16(Bsh + ((size_t)((k0) >> 6) * T_ + t0 + 64 + rl) * 64 + ((k0) & 32) + swz, pSH + 16384 + (b) * 8192 + 4096 + w * 1024); \
    } while (0)

    STAGE_E(0, 0);
    for (int step = 0; step < nsteps; ++step) {
        const int cur = step & 1;
        if (step + 1 < nsteps) {
            STAGE_E(cur ^ 1, (step + 1) * 32);
            asm volatile("s_waitcnt vmcnt(4)" ::: "memory");
        } else {
            asm volatile("s_waitcnt vmcnt(0)" ::: "memory");
        }
        __builtin_amdgcn_s_barrier();
        f16x8 a[4], b[4];
        #pragma unroll
        for (int i = 0; i < 4; ++i) {
            int row = wr * 64 + i * 16 + arow;
            int cc = g ^ ((row >> 1) & 3);
            a[i] = *reinterpret_cast<const f16x8*>(&SH[cur * 4096 + row * 32 + cc * 8]);
        }
        #pragma unroll
        for (int j = 0; j < 4; ++j) {
            int row = wc * 64 + j * 16 + arow;
            int cc = g ^ ((row >> 1) & 3);
            b[j] = *reinterpret_cast<const f16x8*>(&SH[8192 + cur * 4096 + row * 32 + cc * 8]);
        }
        #pragma unroll
        for (int i = 0; i < 4; ++i)
            #pragma unroll
            for (int j = 0; j < 4; ++j)
                acc[i][j] = __builtin_amdgcn_mfma_f32_16x16x32_f16(a[i], b[j], acc[i][j], 0, 0, 0);
        __builtin_amdgcn_s_barrier();
    }
    #undef STAGE_E

    // epilogue: C row = n'', col = t; EO[b][t][n''] as fp16, 8B stores
    const int ccol = lane & 15;
    const int rbase = (lane >> 4) * 4;
    __half* eob = EO + (size_t)b_local * EO_E;
    #pragma unroll
    for (int i = 0; i < 4; ++i) {
        int nb = n0 + wr * 64 + i * 16 + rbase;
        #pragma unroll
        for (int j = 0; j < 4; ++j) {
            int t = t0 + wc * 64 + j * 16 + ccol;
            __half hv[4];
            hv[0] = __float2half(acc[i][j][0]);
            hv[1] = __float2half(acc[i][j][1]);
            hv[2] = __float2half(acc[i][j][2]);
            hv[3] = __float2half(acc[i][j][3]);
            *reinterpret_cast<short4*>(&eob[(size_t)t * NFFT + nb]) =
                *reinterpret_cast<short4*>(hv);
        }
    }
}

// ---------------- gather (x4 vectorized): window * butterfly * OLA / env -> out ----------------
__global__ void gather_kernel(const __half* __restrict__ EO,
                              const float* __restrict__ window,
                              float* __restrict__ out, int b0, int bcount) {
    int o0 = (blockIdx.x * 256 + threadIdx.x) * 4;
    int s = o0 + PAD;
    int m = s >> 8, p = s & 255;
    float env[4] = {1e-11f, 1e-11f, 1e-11f, 1e-11f};
    float wv[4][4]; int tv[4]; float sg[4];
    #pragma unroll
    for (int j = 0; j < 4; ++j) {
        int t = m - j;
        bool ok = (t >= 0) && (t < T_);
        tv[j] = ok ? t : 0;
        sg[j] = (j < 2) ? 1.f : -1.f;
        float4 w4 = ok ? *reinterpret_cast<const float4*>(&window[p + 256 * j])
                       : make_float4(0.f, 0.f, 0.f, 0.f);
        wv[j][0] = w4.x; wv[j][1] = w4.y; wv[j][2] = w4.z; wv[j][3] = w4.w;
        #pragma unroll
        for (int r = 0; r < 4; ++r) env[r] = fmaf(wv[j][r], wv[j][r], env[r]);
    }
    float inv[4];
    #pragma unroll
    for (int r = 0; r < 4; ++r) inv[r] = 1.0f / env[r];

    for (int bl = 0; bl < bcount; ++bl) {
        const __half* eo = EO + (size_t)bl * EO_E;
        float y[4] = {0.f, 0.f, 0.f, 0.f};
        #pragma unroll
        for (int j = 0; j < 4; ++j) {
            const __half* row = eo + (size_t)tv[j] * NFFT + p + 256 * (j & 1);
            ushort4 ue = *reinterpret_cast<const ushort4*>(row);
            ushort4 uo = *reinterpret_cast<const ushort4*>(row + 512);
            float e[4] = {h2f(ue.x), h2f(ue.y), h2f(ue.z), h2f(ue.w)};
            float od[4] = {h2f(uo.x), h2f(uo.y), h2f(uo.z), h2f(uo.w)};
            #pragma unroll
            for (int r = 0; r < 4; ++r)
                y[r] = fmaf(wv[j][r], fmaf(sg[j], od[r], e[r]), y[r]);
        }
        *reinterpret_cast<float4*>(&out[(size_t)(b0 + bl) * OUTB + o0]) =
            make_float4(y[0] * inv[0], y[1] * inv[1], y[2] * inv[2], y[3] * inv[3]);
    }
}

// ---------------- launch ----------------
extern "C" void kernel_launch(void* const* d_in, const int* in_sizes, int n_in,
                              void* d_out, int out_size, void* d_ws, size_t ws_size,
                              hipStream_t stream) {
    const float* x      = (const float*)d_in[0];
    const float* W      = (const float*)d_in[1];
    const float* bias   = (const float*)d_in[2];
    const float* window = (const float*)d_in[3];
    float* out = (float*)d_out;

    const size_t Ae  = (size_t)NFFT * KE;        //   589,824
    const size_t We  = (size_t)NW * H_;          //   294,912

    // Layout: [Ab|Wm|Wp|spec E,O (fp16)|EO(fp16)] ; xh (fp16) aliases EO (validated r12/r14).
    int bcount = B_;
    for (;;) {
        size_t need = (Ae + 2 * We + 2 * (size_t)bcount * SE_E) * sizeof(ushort)
                    + (size_t)bcount * EO_E * sizeof(__half);
        if (need <= ws_size || bcount == 1) break;
        bcount >>= 1;
    }

    ushort* Ab  = (ushort*)d_ws;
    ushort* Wm  = Ab + Ae;
    ushort* Wp  = Wm + We;
    ushort* SEh = Wp + We;
    ushort* SOh = SEh + (size_t)bcount * SE_E;
    __half* EO  = (__half*)(SOh + (size_t)bcount * SE_E);
    ushort* xhb = (ushort*)EO;                     // alias: xh lives in EO region

    basis_kernel<<<(NFFT * KE) / 256, 256, 0, stream>>>(Ab);
    prepw_kernel<<<(NW * H_ + 255) / 256, 256, 0, stream>>>(W, Wm, Wp);

    for (int b0 = 0; b0 < B_; b0 += bcount) {
        convx_kernel<<<(int)((size_t)bcount * T_ * H_ / 8 / 256), 256, 0, stream>>>(x, xhb, b0);
        nyq_kernel<<<dim3(T_ / 64, bcount), 256, 0, stream>>>(xhb, Wm, Wp, bias, SEh);
        dim3 ga(bcount * 256);
        gemm_a_mfma<<<ga, 256, 0, stream>>>(xhb, Wm, Wp, bias, SEh, SOh);
        dim3 ge(256, bcount);
        gemm_eo_mfma<<<ge, 256, 0, stream>>>(Ab, SEh, SOh, EO);
        gather_kernel<<<OUTB / 4 / 256, 256, 0, stream>>>(EO, window, out, b0, bcount);
    }
}

// Round 20
// 174.533 us; speedup vs baseline: 1.0181x; 1.0181x over previous
//
#include <hip/hip_runtime.h>
#include <hip/hip_fp16.h>
#include <math.h>

#define B_  8
#define T_  4096
#define H_  512
#define FREQ 513
#define NW  576            // padded f (9 tiles of 64)
#define KE  576            // spec K: interleaved [re,im], padded; 9 tiles of 64
#define NFFT 1024
#define HOP 256
#define PAD 384
#define OUTB 1048576
#define CLAMP_MAXV 100.0f
#define SE_E ((size_t)T_ * KE)     // spec elems per batch (fp16)
#define EO_E ((size_t)T_ * NFFT)   // EO elems per batch

typedef __attribute__((ext_vector_type(8))) _Float16 f16x8;
typedef __attribute__((ext_vector_type(4))) float f32x4;

__device__ inline ushort f2h(float v) {
    _Float16 h = (_Float16)v;
    ushort u; __builtin_memcpy(&u, &h, 2); return u;
}
__device__ inline float h2f(ushort u) {
    _Float16 h; __builtin_memcpy(&h, &u, 2); return (float)h;
}

#define GLOAD_LDS16(g, l) __builtin_amdgcn_global_load_lds( \
    (const __attribute__((address_space(1))) unsigned int*)(g), \
    (__attribute__((address_space(3))) unsigned int*)(l), 16, 0, 0)

// ---------------- basis (fp16): Ab[r][c]; r<512: E half (k=2kk), r>=512: O half (k=2kk+1) --------
__global__ void basis_kernel(ushort* __restrict__ Ab) {
    int idx = blockIdx.x * 256 + threadIdx.x;   // [0, 1024*576)
    int r = idx / KE, c = idx - r * KE;
    int np = (r < 512) ? r : (r - 512);
    int kk = c >> 1;
    int k = (r < 512) ? (2 * kk) : (2 * kk + 1);
    float v = 0.f;
    bool valid = (r < 512) ? (kk <= 256) : (kk <= 255);
    if (valid) {
        int m = (np * k) & (NFFT - 1);
        float a = (float)m * 6.135923151542565e-3f;       // 2*pi/1024
        float sc = ((k == 0) || (k == 512)) ? (1.0f / NFFT) : (2.0f / NFFT);
        v = ((c & 1) ? -sinf(a) : cosf(a)) * sc;
    }
    Ab[idx] = f2h(v);
}

// ---------------- W prep (fp16): Wm/Wp [f(576)][k(512)], rows >= FREQ zeroed ----------------
__global__ void prepw_kernel(const float* __restrict__ W,
                             ushort* __restrict__ Wm, ushort* __restrict__ Wp) {
    int idx = blockIdx.x * 256 + threadIdx.x;
    if (idx >= NW * H_) return;
    int k = idx / NW, f = idx - k * NW;
    float vm = 0.f, vp = 0.f;
    if (f < FREQ) {
        vm = W[(size_t)k * (2 * FREQ) + f];
        vp = W[(size_t)k * (2 * FREQ) + FREQ + f];
    }
    size_t dst = (size_t)f * H_ + k;
    Wm[dst] = f2h(vm);
    Wp[dst] = f2h(vp);
}

// ---------------- x conversion (fp16, per bcount-chunk) ----------------
__global__ void convx_kernel(const float* __restrict__ x, ushort* __restrict__ xh, int b0) {
    size_t i8 = ((size_t)blockIdx.x * 256 + threadIdx.x) * 8;
    const float* xp = x + (size_t)b0 * T_ * H_ + i8;
    float4 v0 = *reinterpret_cast<const float4*>(xp);
    float4 v1 = *reinterpret_cast<const float4*>(xp + 4);
    float xv[8];
    *reinterpret_cast<float4*>(&xv[0]) = v0;
    *reinterpret_cast<float4*>(&xv[4]) = v1;
    ushort h[8];
    #pragma unroll
    for (int e = 0; e < 8; ++e) h[e] = f2h(xv[e]);
    *reinterpret_cast<ushort4*>(xh + i8)     = make_ushort4(h[0], h[1], h[2], h[3]);
    *reinterpret_cast<ushort4*>(xh + i8 + 4) = make_ushort4(h[4], h[5], h[6], h[7]);
}

// ---------------- GEMM A (fp16 MFMA, 2-phase dbuf + counted vmcnt): 128t x 64f, BK=32 ----------
// grid: 1D bcount*288 (9 f-tiles incl. f=512 tile), XCD-swizzled (f fastest).
__global__ __launch_bounds__(256) void gemm_a_mfma(
    const ushort* __restrict__ xh,
    const ushort* __restrict__ Wm, const ushort* __restrict__ Wp,
    const float* __restrict__ bias,
    ushort* __restrict__ SEh, ushort* __restrict__ SOh)
{
    // ushort idx: X buf b @ b*4096 [128x32]; Wm buf b @ 8192+b*2048; Wp @ 12288+b*2048
    __shared__ __attribute__((aligned(16))) ushort SH[16384];

    const int tid = threadIdx.x;
    const int lane = tid & 63;
    const int w = tid >> 6;
    const int wr = w >> 1, wc = w & 1;
    const int g = lane >> 4;

    const int nwg = gridDim.x;                 // bcount*288, % 8 == 0
    const int wg = blockIdx.x;
    const int gwi = (wg & 7) * (nwg >> 3) + (wg >> 3);
    const int m0 = (gwi / 9) * 128;            // chunk-local t row base
    const int f0 = (gwi % 9) * 64;             // f fastest (tiles 0..8)

    const int rl = tid >> 2;                                  // 0..63 (staging row)
    const int swz = ((tid & 3) ^ ((tid >> 3) & 3)) * 8;       // pre-swizzled src chunk
    const int arow = lane & 15;

    f32x4 accM[4][2] = {};
    f32x4 accP[4][2] = {};
    char* pSH = (char*)SH;

    #define STAGE_A(b, k0) do { \
        GLOAD_LDS16(xh + (size_t)(m0 + rl) * H_ + (k0) + swz,       pSH + (b) * 8192 + w * 1024); \
        GLOAD_LDS16(xh + (size_t)(m0 + 64 + rl) * H_ + (k0) + swz,  pSH + (b) * 8192 + 4096 + w * 1024); \
        GLOAD_LDS16(Wm + (size_t)(f0 + rl) * H_ + (k0) + swz,       pSH + 16384 + (b) * 4096 + w * 1024); \
        GLOAD_LDS16(Wp + (size_t)(f0 + rl) * H_ + (k0) + swz,       pSH + 24576 + (b) * 4096 + w * 1024); \
    } while (0)

    STAGE_A(0, 0);
    #pragma unroll 2
    for (int step = 0; step < 16; ++step) {
        const int cur = step & 1;
        if (step < 15) {
            STAGE_A(cur ^ 1, (step + 1) * 32);
            asm volatile("s_waitcnt vmcnt(4)" ::: "memory");
        } else {
            asm volatile("s_waitcnt vmcnt(0)" ::: "memory");
        }
        __builtin_amdgcn_s_barrier();
        f16x8 ax[4], wm[2], wp[2];
        #pragma unroll
        for (int i = 0; i < 4; ++i) {
            int row = wr * 64 + i * 16 + arow;
            int cc = g ^ ((row >> 1) & 3);
            ax[i] = *reinterpret_cast<const f16x8*>(&SH[cur * 4096 + row * 32 + cc * 8]);
        }
        #pragma unroll
        for (int j = 0; j < 2; ++j) {
            int row = wc * 32 + j * 16 + arow;
            int cc = g ^ ((row >> 1) & 3);
            wm[j] = *reinterpret_cast<const f16x8*>(&SH[8192 + cur * 2048 + row * 32 + cc * 8]);
            wp[j] = *reinterpret_cast<const f16x8*>(&SH[12288 + cur * 2048 + row * 32 + cc * 8]);
        }
        #pragma unroll
        for (int i = 0; i < 4; ++i)
            #pragma unroll
            for (int j = 0; j < 2; ++j) {
                accM[i][j] = __builtin_amdgcn_mfma_f32_16x16x32_f16(ax[i], wm[j], accM[i][j], 0, 0, 0);
                accP[i][j] = __builtin_amdgcn_mfma_f32_16x16x32_f16(ax[i], wp[j], accP[i][j], 0, 0, 0);
            }
        __builtin_amdgcn_s_barrier();
    }
    #undef STAGE_A

    // ---- epilogue: nonlinearity (live f only), then 2-pass (SE, SO) LDS transpose ----
    const int ccol = lane & 15;
    const int rbase = (lane >> 4) * 4;
    const int b_local = m0 >> 12;
    const int t00blk = m0 & (T_ - 1);
    const size_t specoff = (size_t)b_local * SE_E;
    const size_t tilebase = (size_t)(f0 >> 6) * T_ * 64;

    #pragma unroll
    for (int j = 0; j < 2; ++j) {
        int f = f0 + wc * 32 + j * 16 + ccol;
        bool live = (f < FREQ);
        float bm = live ? bias[f] : 0.f;
        float bp = live ? bias[FREQ + f] : 0.f;
        #pragma unroll
        for (int i = 0; i < 4; ++i)
            #pragma unroll
            for (int r = 0; r < 4; ++r) {
                float re = 0.f, im = 0.f;
                if (live) {
                    float mag = fminf(__expf(accM[i][j][r] + bm), CLAMP_MAXV);
                    float phv = accP[i][j][r] + bp;
                    float sp, cp; __sincosf(phv, &sp, &cp);
                    re = mag * cp; im = mag * sp;
                }
                accM[i][j][r] = re; accP[i][j][r] = im;
            }
    }

    const int par_mine = ccol & 1;
    const int row0 = tid >> 3;           // 0..31
    const int c8 = (tid & 7) * 8;
    #pragma unroll
    for (int pass = 0; pass < 2; ++pass) {
        if (par_mine == pass) {
            #pragma unroll
            for (int j = 0; j < 2; ++j) {
                int u = wc * 32 + j * 16 + ccol;
                int kl = u & ~1;
                #pragma unroll
                for (int i = 0; i < 4; ++i) {
                    #pragma unroll
                    for (int r = 0; r < 4; ++r) {
                        int tl = wr * 64 + i * 16 + rbase + r;
                        *reinterpret_cast<ushort2*>(&SH[tl * 72 + kl]) =
                            make_ushort2(f2h(accM[i][j][r]), f2h(accP[i][j][r]));
                    }
                }
            }
        }
        __syncthreads();
        ushort* d = (pass ? SOh : SEh) + specoff + tilebase;
        #pragma unroll
        for (int q2 = 0; q2 < 4; ++q2) {
            int row = q2 * 32 + row0;
            ushort4 v0 = *reinterpret_cast<const ushort4*>(&SH[row * 72 + c8]);
            ushort4 v1 = *reinterpret_cast<const ushort4*>(&SH[row * 72 + c8 + 4]);
            ushort* dp = &d[(size_t)(t00blk + row) * 64 + c8];
            *reinterpret_cast<ushort4*>(dp) = v0;
            *reinterpret_cast<ushort4*>(dp + 4) = v1;
        }
        if (pass == 0) __syncthreads();
    }
}

// ---------------- stage 1 GEMM (fp16 MFMA, 2-phase dbuf + counted vmcnt): EO = basis.spec ------
// grid: (256, bcount), XCD-swizzled. Tile 128n x 128t, BK=32; E 17 / O 16 steps (K trimmed).
__global__ __launch_bounds__(256) void gemm_eo_mfma(
    const ushort* __restrict__ Ab,
    const ushort* __restrict__ SEh, const ushort* __restrict__ SOh,
    __half* __restrict__ EO)
{
    // ushort idx: A buf b @ b*4096 [128x32]; B buf b @ 8192 + b*4096 [128x32]
    __shared__ __attribute__((aligned(16))) ushort SH[16384];
    const int tid = threadIdx.x;
    const int lane = tid & 63;
    const int w = tid >> 6;
    const int wr = w >> 1, wc = w & 1;
    const int g = lane >> 4;

    const int wg = blockIdx.x;                 // 256 = 32t x 8n, % 8 == 0
    const int gwi = (wg & 7) * 32 + (wg >> 3);
    const int t0 = (gwi >> 3) * 128;           // contiguous t per XCD
    const int n0 = (gwi & 7) * 128;            // n fastest
    const int b_local = blockIdx.y;

    const ushort* Bsh = ((n0 < 512) ? SEh : SOh) + (size_t)b_local * SE_E;
    const int nsteps = (n0 < 512) ? 17 : 16;   // E: 544 valid cols; O: 512

    const int rl = tid >> 2;
    const int swz = ((tid & 3) ^ ((tid >> 3) & 3)) * 8;
    const int arow = lane & 15;

    f32x4 acc[4][4] = {};
    char* pSH = (char*)SH;

    #define STAGE_E(b, k0) do { \
        GLOAD_LDS16(Ab + (size_t)(n0 + rl) * KE + (k0) + swz,       pSH + (b) * 8192 + w * 1024); \
        GLOAD_LDS16(Ab + (size_t)(n0 + 64 + rl) * KE + (k0) + swz,  pSH + (b) * 8192 + 4096 + w * 1024); \
        GLOAD_LDS16(Bsh + ((size_t)((k0) >> 6) * T_ + t0 + rl) * 64 + ((k0) & 32) + swz,      pSH + 16384 + (b) * 8192 + w * 1024); \
        GLOAD_LDS16(Bsh + ((size_t)((k0) >> 6) * T_ + t0 + 64 + rl) * 64 + ((k0) & 32) + swz, pSH + 16384 + (b) * 8192 + 4096 + w * 1024); \
    } while (0)

    STAGE_E(0, 0);
    for (int step = 0; step < nsteps; ++step) {
        const int cur = step & 1;
        if (step + 1 < nsteps) {
            STAGE_E(cur ^ 1, (step + 1) * 32);
            asm volatile("s_waitcnt vmcnt(4)" ::: "memory");
        } else {
            asm volatile("s_waitcnt vmcnt(0)" ::: "memory");
        }
        __builtin_amdgcn_s_barrier();
        f16x8 a[4], b[4];
        #pragma unroll
        for (int i = 0; i < 4; ++i) {
            int row = wr * 64 + i * 16 + arow;
            int cc = g ^ ((row >> 1) & 3);
            a[i] = *reinterpret_cast<const f16x8*>(&SH[cur * 4096 + row * 32 + cc * 8]);
        }
        #pragma unroll
        for (int j = 0; j < 4; ++j) {
            int row = wc * 64 + j * 16 + arow;
            int cc = g ^ ((row >> 1) & 3);
            b[j] = *reinterpret_cast<const f16x8*>(&SH[8192 + cur * 4096 + row * 32 + cc * 8]);
        }
        #pragma unroll
        for (int i = 0; i < 4; ++i)
            #pragma unroll
            for (int j = 0; j < 4; ++j)
                acc[i][j] = __builtin_amdgcn_mfma_f32_16x16x32_f16(a[i], b[j], acc[i][j], 0, 0, 0);
        __builtin_amdgcn_s_barrier();
    }
    #undef STAGE_E

    // epilogue: C row = n'', col = t; EO[b][t][n''] as fp16, 8B stores
    const int ccol = lane & 15;
    const int rbase = (lane >> 4) * 4;
    __half* eob = EO + (size_t)b_local * EO_E;
    #pragma unroll
    for (int i = 0; i < 4; ++i) {
        int nb = n0 + wr * 64 + i * 16 + rbase;
        #pragma unroll
        for (int j = 0; j < 4; ++j) {
            int t = t0 + wc * 64 + j * 16 + ccol;
            __half hv[4];
            hv[0] = __float2half(acc[i][j][0]);
            hv[1] = __float2half(acc[i][j][1]);
            hv[2] = __float2half(acc[i][j][2]);
            hv[3] = __float2half(acc[i][j][3]);
            *reinterpret_cast<short4*>(&eob[(size_t)t * NFFT + nb]) =
                *reinterpret_cast<short4*>(hv);
        }
    }
}

// ---------------- gather (x4 vectorized): window * butterfly * OLA / env -> out ----------------
__global__ void gather_kernel(const __half* __restrict__ EO,
                              const float* __restrict__ window,
                              float* __restrict__ out, int b0, int bcount) {
    int o0 = (blockIdx.x * 256 + threadIdx.x) * 4;
    int s = o0 + PAD;
    int m = s >> 8, p = s & 255;
    float env[4] = {1e-11f, 1e-11f, 1e-11f, 1e-11f};
    float wv[4][4]; int tv[4]; float sg[4];
    #pragma unroll
    for (int j = 0; j < 4; ++j) {
        int t = m - j;
        bool ok = (t >= 0) && (t < T_);
        tv[j] = ok ? t : 0;
        sg[j] = (j < 2) ? 1.f : -1.f;
        float4 w4 = ok ? *reinterpret_cast<const float4*>(&window[p + 256 * j])
                       : make_float4(0.f, 0.f, 0.f, 0.f);
        wv[j][0] = w4.x; wv[j][1] = w4.y; wv[j][2] = w4.z; wv[j][3] = w4.w;
        #pragma unroll
        for (int r = 0; r < 4; ++r) env[r] = fmaf(wv[j][r], wv[j][r], env[r]);
    }
    float inv[4];
    #pragma unroll
    for (int r = 0; r < 4; ++r) inv[r] = 1.0f / env[r];

    for (int bl = 0; bl < bcount; ++bl) {
        const __half* eo = EO + (size_t)bl * EO_E;
        float y[4] = {0.f, 0.f, 0.f, 0.f};
        #pragma unroll
        for (int j = 0; j < 4; ++j) {
            const __half* row = eo + (size_t)tv[j] * NFFT + p + 256 * (j & 1);
            ushort4 ue = *reinterpret_cast<const ushort4*>(row);
            ushort4 uo = *reinterpret_cast<const ushort4*>(row + 512);
            float e[4] = {h2f(ue.x), h2f(ue.y), h2f(ue.z), h2f(ue.w)};
            float od[4] = {h2f(uo.x), h2f(uo.y), h2f(uo.z), h2f(uo.w)};
            #pragma unroll
            for (int r = 0; r < 4; ++r)
                y[r] = fmaf(wv[j][r], fmaf(sg[j], od[r], e[r]), y[r]);
        }
        *reinterpret_cast<float4*>(&out[(size_t)(b0 + bl) * OUTB + o0]) =
            make_float4(y[0] * inv[0], y[1] * inv[1], y[2] * inv[2], y[3] * inv[3]);
    }
}

// ---------------- launch ----------------
extern "C" void kernel_launch(void* const* d_in, const int* in_sizes, int n_in,
                              void* d_out, int out_size, void* d_ws, size_t ws_size,
                              hipStream_t stream) {
    const float* x      = (const float*)d_in[0];
    const float* W      = (const float*)d_in[1];
    const float* bias   = (const float*)d_in[2];
    const float* window = (const float*)d_in[3];
    float* out = (float*)d_out;

    const size_t Ae  = (size_t)NFFT * KE;        //   589,824
    const size_t We  = (size_t)NW * H_;          //   294,912

    // Layout: [Ab|Wm|Wp|spec E,O (fp16)|EO(fp16)] ; xh (fp16) aliases EO (validated r12/r14).
    int bcount = B_;
    for (;;) {
        size_t need = (Ae + 2 * We + 2 * (size_t)bcount * SE_E) * sizeof(ushort)
                    + (size_t)bcount * EO_E * sizeof(__half);
        if (need <= ws_size || bcount == 1) break;
        bcount >>= 1;
    }

    ushort* Ab  = (ushort*)d_ws;
    ushort* Wm  = Ab + Ae;
    ushort* Wp  = Wm + We;
    ushort* SEh = Wp + We;
    ushort* SOh = SEh + (size_t)bcount * SE_E;
    __half* EO  = (__half*)(SOh + (size_t)bcount * SE_E);
    ushort* xhb = (ushort*)EO;                     // alias: xh lives in EO region

    basis_kernel<<<(NFFT * KE) / 256, 256, 0, stream>>>(Ab);
    prepw_kernel<<<(NW * H_ + 255) / 256, 256, 0, stream>>>(W, Wm, Wp);

    for (int b0 = 0; b0 < B_; b0 += bcount) {
        convx_kernel<<<(int)((size_t)bcount * T_ * H_ / 8 / 256), 256, 0, stream>>>(x, xhb, b0);
        dim3 ga(bcount * 288);
        gemm_a_mfma<<<ga, 256, 0, stream>>>(xhb, Wm, Wp, bias, SEh, SOh);
        dim3 ge(256, bcount);
        gemm_eo_mfma<<<ge, 256, 0, stream>>>(Ab, SEh, SOh, EO);
        gather_kernel<<<OUTB / 4 / 256, 256, 0, stream>>>(EO, window, out, b0, bcount);
    }
}